// Round 11
// baseline (745.721 us; speedup 1.0000x reference)
//
#include <hip/hip_runtime.h>
#include <hip/hip_bf16.h>

typedef short short8 __attribute__((ext_vector_type(8)));
typedef short sh4    __attribute__((ext_vector_type(4)));
typedef float f32x4  __attribute__((ext_vector_type(4)));
typedef unsigned short us4 __attribute__((ext_vector_type(4)));

#define N_SEQ 8192
#define D_CH  512

constexpr int XSLOTS  = 1152;              // x ring: 1024-row frame + 4-iter margin
constexpr int XLDS_B  = XSLOTS * 8;        // 9216 B (only LDS use)
constexpr int TREV_STRIDE = 8320;          // elems per (r,d) reversed-t array
constexpr size_t TREV_TOT = (size_t)4 * D_CH * TREV_STRIDE;   // 17,039,360 elems

__device__ __forceinline__ unsigned short f32_to_bf16_bits(float f) {
    union { float f; unsigned int u; } v; v.f = f;
    unsigned int u = v.u;
    unsigned int r = u + 0x7FFFu + ((u >> 16) & 1u);   // RNE
    return (unsigned short)(r >> 16);
}
__device__ __forceinline__ float bf16_to_f32(unsigned short u) {
  union { unsigned int u; float f; } v; v.u = ((unsigned int)u) << 16; return v.f;
}
// gelu tanh-approx: y = v * (1 - 1/(exp2(K1*v + K2*v^3) + 1))
__device__ __forceinline__ float gelu_f(float v) {
  float w = v * (2.3022031f + 0.10294296f * v * v);
  float e = __builtin_amdgcn_exp2f(w);
  float r = __builtin_amdgcn_rcpf(e + 1.0f);
  return v - v * r;
}

// ---------------- pre-pass: transpose + cast; t -> 4 shifted reversed arrays ----
// tRev[r][d][u] = t[8228 + r - u]  (zeros outside [0,8191]); pads zeroed by
// dedicated blocks (non-overlapping ranges -> no inter-block race).
__global__ __launch_bounds__(256) void transpose_cast_kernel(
    const float* __restrict__ x, const float* __restrict__ t,
    unsigned short* __restrict__ xT, unsigned short* __restrict__ tRev) {
  __shared__ float tile[64][65];
  int blk = blockIdx.x;
  if (blk >= 5120) {                       // pad-zero blocks: one per d
    int dd = blk - 5120;
    int tid = threadIdx.x;
    #pragma unroll
    for (int rr = 0; rr < 4; ++rr) {
      unsigned short* arr = tRev + ((size_t)(rr * D_CH + dd)) * TREV_STRIDE;
      if (tid < 37 + rr) arr[tid] = 0;                    // u < B_r - 8191
      if (tid < 91 - rr) arr[8229 + rr + tid] = 0;        // u > B_r
    }
    return;
  }
  int bat = blk >> 10;
  int rem = blk & 1023;
  int i0 = (rem >> 3) << 6;
  int d0 = (rem & 7) << 6;
  int tx = threadIdx.x & 63, ty = threadIdx.x >> 6;
  if (bat < 4) {
    const float* src = x + (size_t)bat * N_SEQ * D_CH;
    unsigned short* dst = xT + (size_t)bat * D_CH * N_SEQ;
    #pragma unroll
    for (int r = ty; r < 64; r += 4)
      tile[r][tx] = src[(size_t)(i0 + r) * D_CH + (d0 + tx)];
    __syncthreads();
    #pragma unroll
    for (int r = ty; r < 64; r += 4)
      dst[(size_t)(d0 + r) * N_SEQ + (i0 + tx)] = f32_to_bf16_bits(tile[tx][r]);
  } else {
    #pragma unroll
    for (int r = ty; r < 64; r += 4)
      tile[r][tx] = t[(size_t)(i0 + r) * D_CH + (d0 + tx)];
    __syncthreads();
    #pragma unroll
    for (int r = ty; r < 64; r += 4) {
      unsigned short v = f32_to_bf16_bits(tile[tx][r]);
      int ch = d0 + r, i = i0 + tx;
      #pragma unroll
      for (int rr = 0; rr < 4; ++rr)
        tRev[((size_t)(rr * D_CH + ch)) * TREV_STRIDE + (8228 + rr - i)] = v;
    }
  }
}

// ---------------- output transpose: (d,b,i) bf16 -> (b,i,d) f32 ----------------
__global__ __launch_bounds__(256) void transpose_out_kernel(
    const unsigned short* __restrict__ src, float* __restrict__ dst) {
  __shared__ float tile[64][65];
  int blk = blockIdx.x;
  int b   = blk >> 10;
  int rem = blk & 1023;
  int d0 = (rem & 7) << 6;
  int i0 = (rem >> 3) << 6;
  int tx = threadIdx.x & 63, ty = threadIdx.x >> 6;
  #pragma unroll
  for (int r = ty; r < 64; r += 4)
    tile[r][tx] = bf16_to_f32(src[((size_t)(d0 + r) * 4 + b) * N_SEQ + i0 + tx]);
  __syncthreads();
  #pragma unroll
  for (int r = ty; r < 64; r += 4)
    dst[((size_t)b * N_SEQ + i0 + r) * D_CH + d0 + tx] = tile[tx][r];
}

// ---------------- main kernel ----------------
// 1 wave/block; grid 4096: blk = oct*64 + sblk*8 + (d&7), d = oct*8+(d&7),
// strip = 7-sblk (long strips first within octet). XCD = d%8; all 8 strips of
// a channel run concurrently -> t/x L2-hot.
// No t in LDS: af fragments loaded straight from tRev4 global arrays into a
// 4-deep register pipe afp[4] (2x b64 each, 8B-aligned by array choice rA&3).
// Per iter: 5 VMEM (4 af-b64 + 1 x-DMA); vmcnt(15) = age-4 completion for both.
template<int DMAJOR>
__global__ __launch_bounds__(64, 4) void tno_conv_kernel(
    const unsigned short* __restrict__ xT, const unsigned short* __restrict__ tRev,
    unsigned short* __restrict__ owsp, float* __restrict__ outp) {
  __shared__ __align__(16) char lds[XLDS_B];
  const int lane = threadIdx.x & 63;
  const int blk  = blockIdx.x;
  const int d    = ((blk >> 6) << 3) | (blk & 7);
  const int strip = 7 - ((blk >> 3) & 7);
  const int base  = strip << 10;
  const int l_hi  = base + 960;

  // MFMA lane constants
  const int m      = lane & 15;
  const int kb     = (lane >> 4) << 3;
  const int bcol   = m & 3;
  const int sl     = m >> 2;
  const int rA     = m & 7;
  char* ldsX = lds;
  // x staging lane mapping (DMA dst byte = 4*lane within each 256B region)
  const int uLin = (lane & 3) | ((lane >> 4) << 2);
  const int sb   = (lane >> 2) & 3;
  const unsigned short* xlaneB = xT + (((size_t)sb * D_CH + d) << 13) + (uLin << 1);
  // af global base: S0(l_hi) = B_r - l_hi - (m&8) + kb - rA, B_r = 8228+(rA&3)
  const char* pA = (const char*)(tRev + ((size_t)((rA & 3) * D_CH + d)) * TREV_STRIDE)
                 + 2 * (8228 + (rA & 3) - l_hi - (m & 8) + kb - rA);

  typedef __attribute__((address_space(3))) unsigned int lds_u32;
  typedef const __attribute__((address_space(1))) unsigned int glb_u32;

#define LD2(P, O1, O2)                                                           \
  __builtin_shufflevector(*(const sh4*)((P) + (O1)), *(const sh4*)((P) + (O2)),  \
                          0, 1, 2, 3, 4, 5, 6, 7)

  f32x4 acc[4][4];
  #pragma unroll
  for (int g = 0; g < 4; ++g)
    #pragma unroll
    for (int k = 0; k < 4; ++k)
      acc[g][k] = (f32x4){0.f, 0.f, 0.f, 0.f};

  // ---- af pipe prefill: afp[u] = af(l_hi - 32u); prime af2/af3 = af(l_hi+32)
  short8 afp0[4], afp1[4];
  #pragma unroll
  for (int u = 0; u < 4; ++u) {
    afp0[u] = LD2(pA + (u << 6), 0, 8);
    afp1[u] = LD2(pA + (u << 6), -32, -24);
  }
  short8 af2 = LD2(pA, -64, -56);
  short8 af3 = LD2(pA, -96, -88);
  pA += 256;                         // first in-loop load = af(l_hi-128)

  // ---- x prologue: zero rows [-960,-1] (slots 192..1151, bytes 1536..9215),
  // DMA rows [0,159] (5 chunks)
  {
    f32x4 z = (f32x4){0.f, 0.f, 0.f, 0.f};
    #pragma unroll
    for (int j = 0; j < 7; ++j)
      *(f32x4*)(ldsX + 1536 + (j << 10) + (lane << 4)) = z;
    *(unsigned long long*)(ldsX + 8704 + (lane << 3)) = 0ull;
    #pragma unroll
    for (int j = 0; j < 5; ++j)
      __builtin_amdgcn_global_load_lds((glb_u32*)(const void*)(xlaneB + (j << 5)),
                                       (lds_u32*)(void*)(ldsX + (j << 8)), 4, 0, 0);
  }
  asm volatile("s_waitcnt vmcnt(0)" ::: "memory");

  // ---- loop state
  int xo[4];
  #pragma unroll
  for (int g = 0; g < 4; ++g) {
    int row = (base - l_hi) + (g << 8) + (sl << 6) + kb;   // in [-960, 24]
    if (row < 0) row += XSLOTS;
    xo[g] = (row << 3) + (bcol << 4);
  }
  const unsigned short* xsp = xlaneB + 160;    // next DMA: rows [160,191]
  int wb = 1280;                               // slot 160 * 8

#define CONV_ITER(GMIN, U)                                                       \
  {                                                                              \
    asm volatile("s_waitcnt vmcnt(15)" ::: "memory");                            \
    __builtin_amdgcn_global_load_lds((glb_u32*)(const void*)xsp,                 \
        (lds_u32*)(void*)(ldsX + wb), 4, 0, 0);                                  \
    short8 a0 = afp0[U], a1 = afp1[U];                                           \
    __builtin_amdgcn_s_setprio(1);                                               \
    _Pragma("unroll")                                                            \
    for (int g = 0; g < 4; ++g) {                                                \
      if (g >= (GMIN)) {                                                         \
        short8 bf = *(const short8*)(ldsX + xo[g]);                              \
        acc[g][0] = __builtin_amdgcn_mfma_f32_16x16x32_bf16(a0,  bf, acc[g][0], 0, 0, 0); \
        acc[g][1] = __builtin_amdgcn_mfma_f32_16x16x32_bf16(a1,  bf, acc[g][1], 0, 0, 0); \
        acc[g][2] = __builtin_amdgcn_mfma_f32_16x16x32_bf16(af2, bf, acc[g][2], 0, 0, 0); \
        acc[g][3] = __builtin_amdgcn_mfma_f32_16x16x32_bf16(af3, bf, acc[g][3], 0, 0, 0); \
      }                                                                          \
      xo[g] += 256; if (xo[g] >= XLDS_B) xo[g] -= XLDS_B;                        \
    }                                                                            \
    __builtin_amdgcn_s_setprio(0);                                               \
    afp0[U] = LD2(pA, 0, 8);                                                     \
    afp1[U] = LD2(pA, -32, -24);                                                 \
    pA += 64;                                                                    \
    af2 = a0; af3 = a1;                                                          \
    xsp += 32;                                                                   \
    wb += 256; if (wb >= XLDS_B) wb -= XLDS_B;                                   \
  }

#define PH4(GMIN)                                                                \
    { _Pragma("unroll")                                                          \
      for (int u = 0; u < 4; ++u) CONV_ITER(GMIN, u) }

  PH4(3) PH4(3)                           // l = base+960 .. base+736
  PH4(2) PH4(2)                           // l = base+704 .. base+480
  PH4(1) PH4(1)                           // l = base+448 .. base+224
  const int n0 = (strip << 3) + 2;        // (32*strip+8)/4 blocks of 4
  #pragma unroll 1
  for (int c4 = 0; c4 < n0; ++c4)
    PH4(0)                                // l = base+192 .. -32
#undef PH4
#undef CONV_ITER
#undef LD2

  // drain in-flight DMA so nothing lands in a successor block's LDS
  asm volatile("s_waitcnt vmcnt(0)" ::: "memory");

  // ---- epilogue: gelu + store ----
  if (DMAJOR) {
    unsigned short* op = owsp + ((((size_t)d << 2) + bcol) << 13) + base
                       + (sl << 6) + ((lane >> 4) << 2);
    #pragma unroll
    for (int g = 0; g < 4; ++g)
      #pragma unroll
      for (int k = 0; k < 4; ++k) {
        us4 w;
        #pragma unroll
        for (int r = 0; r < 4; ++r)
          w[r] = f32_to_bf16_bits(gelu_f(acc[g][k][r]));
        *(us4*)(op + (g << 8) + (k << 4)) = w;
      }
  } else {
    #pragma unroll
    for (int g = 0; g < 4; ++g)
      #pragma unroll
      for (int k = 0; k < 4; ++k)
        #pragma unroll
        for (int r = 0; r < 4; ++r) {
          int i = base + (((g << 2) + sl) << 6) + (k << 4) + ((lane >> 4) << 2) + r;
          outp[(((size_t)bcol << 13) + (size_t)i) * D_CH + d] = gelu_f(acc[g][k][r]);
        }
  }
}

extern "C" void kernel_launch(void* const* d_in, const int* in_sizes, int n_in,
                              void* d_out, int out_size, void* d_ws, size_t ws_size,
                              hipStream_t stream) {
  const float* x = (const float*)d_in[0];
  const float* t = (const float*)d_in[1];
  float* out = (float*)d_out;

  const size_t xT_elems = (size_t)4 * D_CH * N_SEQ;       // bf16
  unsigned short* xT   = (unsigned short*)d_ws;
  unsigned short* tRev = xT + xT_elems;
  unsigned short* ows  = tRev + TREV_TOT;                 // bf16 intermediate
  const size_t need = (xT_elems + TREV_TOT + xT_elems) * 2;   // ~101 MB
  const bool dmaj = (ws_size >= need);

  hipLaunchKernelGGL(transpose_cast_kernel, dim3(5632), dim3(256), 0, stream,
                     x, t, xT, tRev);
  if (dmaj) {
    hipLaunchKernelGGL((tno_conv_kernel<1>), dim3(4096), dim3(64), 0, stream,
                       xT, tRev, ows, out);
    hipLaunchKernelGGL(transpose_out_kernel, dim3(4096), dim3(256), 0, stream,
                       ows, out);
  } else {
    hipLaunchKernelGGL((tno_conv_kernel<0>), dim3(4096), dim3(64), 0, stream,
                       xT, tRev, ows, out);
  }
}